// Round 6
// baseline (525.118 us; speedup 1.0000x reference)
//
#include <hip/hip_runtime.h>
#include <math.h>

#define VOCAB   5000
#define T_CTC   512
#define S_TGT   128
#define BATCH   16
#define ALPHA_W 0.2f
#define CONF    0.9f            // 1 - smoothing
#define OFFV    (0.1f / 4999.0f)
#define CHUNK   32              // timesteps per ready-flag chunk
#define NCHUNK  16              // 16 * 32 = 512 timesteps
#define CSTR    132             // compact row stride (floats)

// ws layout (32-bit word indices)
#define WS_CNT   0              // u32[256]  : cnt[b*16 + chunk], target 8
#define WS_DONE  256            // u32[1]    : done-block counter
#define WS_ATT   512            // f32[2048] : att per-row partials
#define WS_CTC   2560           // f32[16]   : ctc per-batch losses
#define WS_CBUF  4096           // f32[16*512*132] : compact emissions

#define GATHER_BLKS 2048        // 16 b x 128 t-quads
#define CTC_BLKS    16
#define ATT_BLKS    2048
#define DONE_TARGET (CTC_BLKS + ATT_BLKS)   // 2064

#define STEP(j) {                                                   \
    double E1 = (double)Ej[j].x, E3 = (double)Ej[j].y;              \
    double p3 = __shfl_up(b3, 1, 64); p3 = (k == 0) ? 0.0 : p3;     \
    double n0 = b0 + p3;                                            \
    double n1 = (b1 + b0 + g1 * p3) * E1;                           \
    double n2 = b2 + b1;                                            \
    double n3 = (b3 + b2 + g3 * b1) * E3;                           \
    double n4 = b4 + b3;                                            \
    b0 = n0; b1 = n1; b2 = n2; b3 = n3; b4 = n4; }

#define GROUP(N, R0, BSEL) {                                        \
    float2 Ej[N];                                                   \
    _Pragma("unroll")                                               \
    for (int j = 0; j < (N); ++j)                                   \
        Ej[j] = *(const float2*)&ebuf[BSEL][(R0) + j][2 * k];       \
    _Pragma("unroll")                                               \
    for (int j = 0; j < (N); ++j) STEP(j) }

__global__ __launch_bounds__(512)
void fused_kernel(const float* __restrict__ ctc,
                  const float* __restrict__ att,
                  const int*   __restrict__ tgt,
                  float*       __restrict__ ws,
                  unsigned int* __restrict__ wsu,
                  float*       __restrict__ out)
{
    __shared__ __align__(16) float ebuf[2][CHUNK][130]; // 33.3 KB, E-values
    __shared__ int    tgS[S_TGT];
    __shared__ double e0sumS[NCHUNK];
    __shared__ int    islast;
    __shared__ float  wsumS[8];

    const int tid  = threadIdx.x;
    const int wave = tid >> 6;
    const int lane = tid & 63;

    if (blockIdx.x < GATHER_BLKS) {
        // ============ gather: block = (b, quad of 4 timesteps) ============
        const int b  = blockIdx.x >> 7;
        const int q  = blockIdx.x & 127;
        const int t0 = 4 * q;
        if (tid < S_TGT) tgS[tid] = tgt[b * S_TGT + tid];
        __syncthreads();
        const float* lp   = ctc + (size_t)b * T_CTC * VOCAB;
        float*       cbuf = ws + WS_CBUF + (size_t)b * T_CTC * CSTR;
        for (int v = tid; v < 4 * 129; v += 512) {
            const int tt  = v / 129;
            const int idx = v - tt * 129;
            const int col = (idx < 128) ? tgS[idx] : 0;
            cbuf[(size_t)(t0 + tt) * CSTR + idx] = lp[(size_t)(t0 + tt) * VOCAB + col];
        }
        __syncthreads();
        if (tid == 0)
            __hip_atomic_fetch_add(&wsu[WS_CNT + b * 16 + (t0 >> 5)], 1u,
                                   __ATOMIC_RELEASE, __HIP_MEMORY_SCOPE_AGENT);
        return;                                     // gather blocks don't hit done-counter
    }

    if (blockIdx.x < GATHER_BLKS + CTC_BLKS) {
        // ============ CTC recursion: one batch per block ============
        const int b = blockIdx.x - GATHER_BLKS;
        unsigned int* cnt = &wsu[WS_CNT + b * 16];
        const float* cbuf = ws + WS_CBUF + (size_t)b * T_CTC * CSTR;

        if (tid < S_TGT) tgS[tid] = tgt[b * S_TGT + tid];
        __syncthreads();

        // consumer constants: lane k owns states 4k..4k+3 (+256 on lane 63)
        const int k  = lane;
        const int t1 = tgS[2 * k];
        const int t3 = tgS[2 * k + 1];
        const int tp = (k > 0) ? tgS[2 * k - 1] : 0;
        const double g1 = ((k > 0) && (t1 != 0) && (t1 != tp)) ? 1.0 : 0.0;
        const double g3 = ((t3 != 0) && (t3 != t1)) ? 1.0 : 0.0;

        // ---- prologue: wait chunk 0, transform rows 1..31, init from row 0 ----
        if (lane == 0) {
            while (__hip_atomic_load(&cnt[0], __ATOMIC_RELAXED,
                                     __HIP_MEMORY_SCOPE_AGENT) < 8u)
                __builtin_amdgcn_s_sleep(2);
        }
        __threadfence();                            // acquire
        for (int idx = tid; idx < CHUNK * 128; idx += 512) {
            const int row = idx >> 7, s = idx & 127;
            if (row >= 1) {
                const float* cr = cbuf + (size_t)row * CSTR;
                ebuf[0][row][s] = __expf(cr[s] - cr[128]);
            }
        }
        if (wave == 1) {                            // e0-sum of chunk 0 (rows 1..31)
            double v = (lane >= 1 && lane < 32) ? (double)cbuf[(size_t)lane * CSTR + 128] : 0.0;
            #pragma unroll
            for (int off = 32; off > 0; off >>= 1) v += __shfl_down(v, off, 64);
            if (lane == 0) e0sumS[0] = v;
        }
        const double e00 = (double)cbuf[128];       // t=0 blank
        double b0 = (k == 0) ? 1.0 : 0.0;
        double b1 = (k == 0) ? (double)__expf(cbuf[0] - (float)e00) : 0.0;
        double b2 = 0.0, b3 = 0.0, b4 = 0.0;
        __syncthreads();

        // ---- main loop: wave0 consumes chunk c; waves 1-7 prep chunk c+1 ----
        for (int c = 0; c < NCHUNK; ++c) {
            const int bs = c & 1;
            if (wave == 0) {
                if (c == 0)      { GROUP(7, 1, 0)  GROUP(8, 8, 0)  GROUP(8, 16, 0)  GROUP(8, 24, 0) }
                else             { GROUP(8, 0, bs) GROUP(8, 8, bs) GROUP(8, 16, bs) GROUP(8, 24, bs) }
            } else if (c + 1 < NCHUNK) {
                const int nb    = bs ^ 1;
                const int cbase = (c + 1) * CHUNK;
                if (lane == 0) {
                    while (__hip_atomic_load(&cnt[c + 1], __ATOMIC_RELAXED,
                                             __HIP_MEMORY_SCOPE_AGENT) < 8u)
                        __builtin_amdgcn_s_sleep(2);
                }
                __threadfence();                    // acquire
                for (int idx = tid - 64; idx < CHUNK * 128; idx += 448) {
                    const int row = idx >> 7, s = idx & 127;
                    const float* cr = cbuf + (size_t)(cbase + row) * CSTR;
                    ebuf[nb][row][s] = __expf(cr[s] - cr[128]);
                }
                if (wave == 1) {
                    double v = (lane < 32) ? (double)cbuf[(size_t)(cbase + lane) * CSTR + 128] : 0.0;
                    #pragma unroll
                    for (int off = 32; off > 0; off >>= 1) v += __shfl_down(v, off, 64);
                    if (lane == 0) e0sumS[c + 1] = v;
                }
            }
            __syncthreads();
        }

        if (wave == 0 && k == 63) {
            double M = e00;
            #pragma unroll
            for (int c = 0; c < NCHUNK; ++c) M += e0sumS[c];
            const double ll = M + log(b3 + b4);     // states 255, 256
            float loss_b = (float)(-ll);
            if (!(loss_b <= 1e20f)) loss_b = 0.0f;  // zero_infinity
            ws[WS_CTC + b] = loss_b;
        }
    } else {
        // ============ label-smoothing row ============
        const int rr = blockIdx.x - (GATHER_BLKS + CTC_BLKS);   // 0..2047
        const float* row = att + (size_t)rr * VOCAB;
        const float4* row4 = (const float4*)row;                // 1250 exact

        float sum = 0.0f;
        for (int i = tid; i < VOCAB / 4; i += 512) {
            float4 v = row4[i];
            sum += v.x + v.y + v.z + v.w;
        }
        #pragma unroll
        for (int off = 32; off > 0; off >>= 1)
            sum += __shfl_down(sum, off, 64);
        if (lane == 0) wsumS[wave] = sum;
        __syncthreads();
        if (tid == 0) {
            float rs = 0.0f;
            #pragma unroll
            for (int i = 0; i < 8; ++i) rs += wsumS[i];
            const float tl = row[tgt[rr]];
            ws[WS_ATT + rr] = -(CONF * tl + OFFV * (rs - tl));
        }
    }

    // ============ completion: last att/ctc block reduces everything ============
    __syncthreads();                                // drain all stores in block
    if (tid == 0) {
        __threadfence();                            // release partials
        unsigned int old = __hip_atomic_fetch_add(&wsu[WS_DONE], 1u,
                               __ATOMIC_ACQ_REL, __HIP_MEMORY_SCOPE_AGENT);
        islast = (old == DONE_TARGET - 1);
    }
    __syncthreads();
    if (!islast) return;
    __threadfence();                                // acquire

    float s_att = 0.0f;
    for (int i = tid; i < ATT_BLKS; i += 512) s_att += ws[WS_ATT + i];
    float s_ctc = (tid < BATCH) ? ws[WS_CTC + tid] : 0.0f;
    #pragma unroll
    for (int off = 32; off > 0; off >>= 1) {
        s_att += __shfl_down(s_att, off, 64);
        s_ctc += __shfl_down(s_ctc, off, 64);
    }
    __syncthreads();                                // wsumS reuse
    if (lane == 0) { wsumS[wave] = s_att; if (wave == 0) e0sumS[0] = (double)s_ctc; }
    __syncthreads();
    if (tid == 0) {
        float sa = 0.0f;
        #pragma unroll
        for (int i = 0; i < 8; ++i) sa += wsumS[i];
        const float sc  = (float)e0sumS[0];
        const float inv = 1.0f / (float)(BATCH * S_TGT);    // both / 2048
        out[0] = ALPHA_W * (sa * inv) + (1.0f - ALPHA_W) * (sc * inv);
    }
}

extern "C" void kernel_launch(void* const* d_in, const int* in_sizes, int n_in,
                              void* d_out, int out_size, void* d_ws, size_t ws_size,
                              hipStream_t stream)
{
    const float* att = (const float*)d_in[0];
    const float* ctc = (const float*)d_in[1];
    const int*   tgt = (const int*)d_in[2];
    float*        out = (float*)d_out;
    float*        ws  = (float*)d_ws;
    unsigned int* wsu = (unsigned int*)d_ws;

    // zero flag/done counters (first 2048 B; partial/cbuf regions need no init)
    hipMemsetAsync(d_ws, 0, 2048, stream);
    fused_kernel<<<GATHER_BLKS + CTC_BLKS + ATT_BLKS, 512, 0, stream>>>(
        ctc, att, tgt, ws, wsu, out);
}

// Round 7
// 291.873 us; speedup vs baseline: 1.7991x; 1.7991x over previous
//
#include <hip/hip_runtime.h>
#include <math.h>

#define VOCAB   5000
#define T_CTC   512
#define S_TGT   128
#define BATCH   16
#define ALPHA_W 0.2f
#define CONF    0.9f            // 1 - smoothing
#define OFFV    (0.1f / 4999.0f)
#define CHUNK   64
#define NCHUNK  8               // chunks cover t = 1..511 (last chunk has 63 rows)
#define CSTR    132             // compact row stride in global (floats)

// ws float-index layout (no init required anywhere)
#define WS_ATT   0              // f32[2048] att per-row partials
#define WS_CTC   2048           // f32[16]   ctc per-batch losses
#define WS_CBUF  4096           // f32[16*512*132] compact emissions

#define GATHER_BLKS 4096        // 16 b x 256 t-pairs
#define ATT_N       2048

// ---------------------------------------------------------------------------
// Kernel A: device-wide gather of emission columns + attention row losses.
// ---------------------------------------------------------------------------
__global__ __launch_bounds__(256)
void gather_att_kernel(const float* __restrict__ ctc,
                       const float* __restrict__ att,
                       const int*   __restrict__ tgt,
                       float*       __restrict__ ws)
{
    if (blockIdx.x < GATHER_BLKS) {
        const int b     = blockIdx.x >> 8;
        const int tpair = blockIdx.x & 255;
        const int t0    = 2 * tpair;
        const float* lp   = ctc + (size_t)b * T_CTC * VOCAB;
        const int*   tg   = tgt + b * S_TGT;
        float*       cbuf = ws + WS_CBUF + (size_t)b * T_CTC * CSTR;

        for (int v = threadIdx.x; v < 258; v += 256) {
            const int tt  = (v >= 129) ? 1 : 0;
            const int idx = v - 129 * tt;
            const int col = (idx < 128) ? tg[idx] : 0;     // idx 128 = blank
            cbuf[(size_t)(t0 + tt) * CSTR + idx] = lp[(size_t)(t0 + tt) * VOCAB + col];
        }
        return;
    }

    // ---- label-smoothing row ----
    const int rr = blockIdx.x - GATHER_BLKS;               // 0..2047
    const float* row = att + (size_t)rr * VOCAB;
    const float4* row4 = (const float4*)row;               // 1250 float4 exact

    float sum = 0.0f;
    for (int i = threadIdx.x; i < VOCAB / 4; i += 256) {
        float4 v = row4[i];
        sum += v.x + v.y + v.z + v.w;
    }
    #pragma unroll
    for (int off = 32; off > 0; off >>= 1)
        sum += __shfl_down(sum, off, 64);

    __shared__ float wsum[4];
    if ((threadIdx.x & 63) == 0) wsum[threadIdx.x >> 6] = sum;
    __syncthreads();
    if (threadIdx.x == 0) {
        const float rs = wsum[0] + wsum[1] + wsum[2] + wsum[3];
        const float tl = row[tgt[rr]];
        ws[WS_ATT + rr] = -(CONF * tl + OFFV * (rs - tl));
    }
}

// ---------------------------------------------------------------------------
// Kernel B: CTC recursion. Producers (waves 1-7) convert raw emissions to
// E = exp(e - e0) in LDS and wave 1 pre-reduces blank sums; consumer (wave 0)
// runs a pure-f64 serial chain out of LDS.
// ---------------------------------------------------------------------------
#define STEP(j) {                                                   \
    double E1 = (double)Ej[j].x, E3 = (double)Ej[j].y;              \
    double p3 = __shfl_up(b3, 1, 64); p3 = (k == 0) ? 0.0 : p3;     \
    double n0 = b0 + p3;                                            \
    double n1 = (b1 + b0 + g1 * p3) * E1;                           \
    double n2 = b2 + b1;                                            \
    double n3 = (b3 + b2 + g3 * b1) * E3;                           \
    double n4 = b4 + b3;                                            \
    b0 = n0; b1 = n1; b2 = n2; b3 = n3; b4 = n4; }

#define GROUP(N, R0) {                                              \
    float2 Ej[N];                                                   \
    _Pragma("unroll")                                               \
    for (int j = 0; j < (N); ++j)                                   \
        Ej[j] = *(const float2*)&ebuf[bs][(R0) + j][2 * k];         \
    _Pragma("unroll")                                               \
    for (int j = 0; j < (N); ++j) STEP(j) }

__global__ __launch_bounds__(512)
void ctc_kernel(const int* __restrict__ tgt, float* __restrict__ ws)
{
    __shared__ __align__(16) float ebuf[2][CHUNK][128];    // 65.5 KB of E-values
    __shared__ double e0sumS[NCHUNK];

    const int b    = blockIdx.x;
    const int tid  = threadIdx.x;
    const int wave = tid >> 6;
    const int lane = tid & 63;
    const int*   tg   = tgt + b * S_TGT;
    const float* cbuf = ws + WS_CBUF + (size_t)b * T_CTC * CSTR;

    // ---- prologue: all 8 waves produce chunk 0 (t = 1..64) ----
    for (int idx = tid; idx < CHUNK * 128; idx += 512) {
        const int row = idx >> 7, s = idx & 127;
        const float* cr = cbuf + (size_t)(1 + row) * CSTR;
        ebuf[0][row][s] = __expf(cr[s] - cr[128]);
    }
    if (wave == 1) {                                       // blank-sum of t=1..64
        double v = (double)cbuf[(size_t)(1 + lane) * CSTR + 128];
        #pragma unroll
        for (int off = 32; off > 0; off >>= 1) v += __shfl_down(v, off, 64);
        if (lane == 0) e0sumS[0] = v;
    }

    // ---- consumer constants: lane k owns states 4k..4k+3 (+256 on lane 63) ----
    const int k  = lane;
    const int t1 = tg[2 * k];
    const int t3 = tg[2 * k + 1];
    const int tp = (k > 0) ? tg[2 * k - 1] : 0;
    const double g1 = ((k > 0) && (t1 != 0) && (t1 != tp)) ? 1.0 : 0.0;
    const double g3 = ((t3 != 0) && (t3 != t1)) ? 1.0 : 0.0;

    const float e00 = cbuf[128];                           // t=0 blank
    double b0 = (k == 0) ? 1.0 : 0.0;
    double b1 = (k == 0) ? (double)__expf(cbuf[0] - e00) : 0.0;
    double b2 = 0.0, b3 = 0.0, b4 = 0.0;
    __syncthreads();

    // ---- main loop: wave 0 consumes chunk c; waves 1-7 produce chunk c+1 ----
    for (int c = 0; c < NCHUNK; ++c) {
        const int bs = c & 1;
        if (wave == 0) {
            if (c < NCHUNK - 1) {
                GROUP(8, 0)  GROUP(8, 8)  GROUP(8, 16) GROUP(8, 24)
                GROUP(8, 32) GROUP(8, 40) GROUP(8, 48) GROUP(8, 56)
            } else {                                       // last chunk: 63 steps
                GROUP(8, 0)  GROUP(8, 8)  GROUP(8, 16) GROUP(8, 24)
                GROUP(8, 32) GROUP(8, 40) GROUP(8, 48) GROUP(7, 56)
            }
        } else if (c + 1 < NCHUNK) {
            const int nb    = bs ^ 1;
            const int tbase = 1 + (c + 1) * CHUNK;
            const int rows  = min(CHUNK, T_CTC - tbase);   // 64, last chunk 63
            for (int idx = tid - 64; idx < rows * 128; idx += 448) {
                const int row = idx >> 7, s = idx & 127;
                const float* cr = cbuf + (size_t)(tbase + row) * CSTR;
                ebuf[nb][row][s] = __expf(cr[s] - cr[128]);
            }
            if (wave == 1) {
                double v = (lane < rows) ? (double)cbuf[(size_t)(tbase + lane) * CSTR + 128] : 0.0;
                #pragma unroll
                for (int off = 32; off > 0; off >>= 1) v += __shfl_down(v, off, 64);
                if (lane == 0) e0sumS[c + 1] = v;
            }
        }
        __syncthreads();
    }

    if (wave == 0 && k == 63) {
        double M = (double)e00;
        #pragma unroll
        for (int c = 0; c < NCHUNK; ++c) M += e0sumS[c];
        const double ll = M + log(b3 + b4);                // states 255, 256
        float loss_b = (float)(-ll);
        if (!(loss_b <= 1e20f)) loss_b = 0.0f;             // zero_infinity
        ws[WS_CTC + b] = loss_b;
    }
}

// ---------------------------------------------------------------------------
// Kernel C: final reduction of 2048 att partials + 16 ctc losses.
// ---------------------------------------------------------------------------
__global__ __launch_bounds__(256)
void combine_kernel(const float* __restrict__ ws, float* __restrict__ out)
{
    const int tid = threadIdx.x;
    float s_att = 0.0f;
    for (int i = tid; i < ATT_N; i += 256) s_att += ws[WS_ATT + i];
    float s_ctc = (tid < BATCH) ? ws[WS_CTC + tid] : 0.0f;

    #pragma unroll
    for (int off = 32; off > 0; off >>= 1) {
        s_att += __shfl_down(s_att, off, 64);
        s_ctc += __shfl_down(s_ctc, off, 64);
    }
    __shared__ float wa[4], wc[4];
    if ((tid & 63) == 0) { wa[tid >> 6] = s_att; wc[tid >> 6] = s_ctc; }
    __syncthreads();
    if (tid == 0) {
        const float inv = 1.0f / (float)ATT_N;             // both sums / 2048
        const float a = (wa[0] + wa[1] + wa[2] + wa[3]) * inv;
        const float c = (wc[0] + wc[1] + wc[2] + wc[3]) * inv;
        out[0] = ALPHA_W * a + (1.0f - ALPHA_W) * c;
    }
}

extern "C" void kernel_launch(void* const* d_in, const int* in_sizes, int n_in,
                              void* d_out, int out_size, void* d_ws, size_t ws_size,
                              hipStream_t stream)
{
    const float* att = (const float*)d_in[0];
    const float* ctc = (const float*)d_in[1];
    const int*   tgt = (const int*)d_in[2];
    float* out = (float*)d_out;
    float* ws  = (float*)d_ws;

    gather_att_kernel<<<GATHER_BLKS + ATT_N, 256, 0, stream>>>(ctc, att, tgt, ws);
    ctc_kernel<<<BATCH, 512, 0, stream>>>(tgt, ws);
    combine_kernel<<<1, 256, 0, stream>>>(ws, out);
}